// Round 10
// baseline (272.923 us; speedup 1.0000x reference)
//
#include <hip/hip_runtime.h>

#define LN_EPS 1e-5f

typedef __attribute__((ext_vector_type(4))) short short4v;
typedef __attribute__((ext_vector_type(4))) float float4v;

__device__ __forceinline__ float wave_sum(float v) {
#pragma unroll
  for (int o = 32; o > 0; o >>= 1) v += __shfl_xor(v, o, 64);
  return v;
}

__device__ __forceinline__ unsigned short f2b(float f) {
  unsigned int u = __float_as_uint(f);
  u += 0x7fffu + ((u >> 16) & 1u);
  return (unsigned short)(u >> 16);
}

__device__ __forceinline__ float b2f(unsigned short h) {
  return __uint_as_float(((unsigned int)h) << 16);
}

__device__ __forceinline__ float4v mfma_16x16x16_bf16(short4v a, short4v b,
                                                      float4v c) {
#if __has_builtin(__builtin_amdgcn_mfma_f32_16x16x16bf16_1k)
  return __builtin_amdgcn_mfma_f32_16x16x16bf16_1k(a, b, c, 0, 0, 0);
#else
  float4v d;
  asm volatile(
      "v_mfma_f32_16x16x16_bf16 %0, %1, %2, %3\n\ts_nop 7\n\ts_nop 7"
      : "=v"(d)
      : "v"(a), "v"(b), "v"(c));
  return d;
#endif
}

// ---------------------------------------------------------------------------
// S1: adj_part (blocks 0..511)  U  qkv projection (blocks 512..767).
// ---------------------------------------------------------------------------
__global__ __launch_bounds__(256) void s1_kernel(
    const float* __restrict__ adj, float* __restrict__ ps,
    float* __restrict__ pss, const float* __restrict__ value,
    const float* __restrict__ keyt, const float* __restrict__ query,
    const float* __restrict__ Wv, const float* __restrict__ Wk,
    const float* __restrict__ Wq, unsigned short* __restrict__ vt,
    unsigned short* __restrict__ kh, unsigned short* __restrict__ qh) {
  __shared__ float r1[4], r2[4];
  __shared__ __align__(16) float wv[256], wk[256], wq[256];
  const int b = blockIdx.x, tid = threadIdx.x;
  if (b < 512) {
    float v0 = adj[b * 512 + tid], v1 = adj[b * 512 + 256 + tid];
    float s = v0 + v1;
    float ss = fmaf(v0, v0, v1 * v1);
    s = wave_sum(s);
    ss = wave_sum(ss);
    if ((tid & 63) == 0) { r1[tid >> 6] = s; r2[tid >> 6] = ss; }
    __syncthreads();
    if (tid == 0) {
      ps[b] = r1[0] + r1[1] + r1[2] + r1[3];
      pss[b] = r2[0] + r2[1] + r2[2] + r2[3];
    }
  } else {
    wv[tid] = Wv[tid];
    wk[tid] = Wk[tid];
    wq[tid] = Wq[tid] * 0.125f;
    __syncthreads();
    const int th = b - 512;
    const int t = th >> 2, h = th & 3;
    const int base = t * 64 + h * 16;
    float y[16];
    unsigned short tmp[16];

#define XFORM(SRC, WARR)                                            \
  {                                                                 \
    const float4* p = (const float4*)(SRC + n * 4096 + base);       \
    float x[16];                                                    \
    *(float4*)(x + 0) = p[0];                                       \
    *(float4*)(x + 4) = p[1];                                       \
    *(float4*)(x + 8) = p[2];                                       \
    *(float4*)(x + 12) = p[3];                                      \
    _Pragma("unroll") for (int d = 0; d < 16; ++d) {                \
      float acc = 0.f;                                              \
      _Pragma("unroll") for (int e4 = 0; e4 < 4; ++e4) {            \
        float4 w4 = *(const float4*)&WARR[d * 16 + e4 * 4];         \
        acc = fmaf(w4.x, x[e4 * 4 + 0], acc);                       \
        acc = fmaf(w4.y, x[e4 * 4 + 1], acc);                       \
        acc = fmaf(w4.z, x[e4 * 4 + 2], acc);                       \
        acc = fmaf(w4.w, x[e4 * 4 + 3], acc);                       \
      }                                                             \
      y[d] = acc;                                                   \
    }                                                               \
  }

    for (int s = 0; s < 2; ++s) {
      const int n = tid + (s << 8);
      XFORM(value, wv)
#pragma unroll
      for (int d = 0; d < 16; ++d) vt[th * 8192 + d * 512 + n] = f2b(y[d]);
      XFORM(keyt, wk)
#pragma unroll
      for (int d = 0; d < 16; ++d) tmp[d] = f2b(y[d]);
      *(int4*)&kh[(th * 512 + n) * 16] = *(int4*)&tmp[0];
      *(int4*)&kh[(th * 512 + n) * 16 + 8] = *(int4*)&tmp[8];
      XFORM(query, wq)
#pragma unroll
      for (int d = 0; d < 16; ++d) tmp[d] = f2b(y[d]);
      *(int4*)&qh[(th * 512 + n) * 16] = *(int4*)&tmp[0];
      *(int4*)&qh[(th * 512 + n) * 16 + 8] = *(int4*)&tmp[8];
    }
#undef XFORM
  }
}

// ---------------------------------------------------------------------------
// S2: prep (blocks 0..899)  U  MFMA attention (blocks 900..1923).
// ---------------------------------------------------------------------------
#define VPAD 536
__global__ __launch_bounds__(256) void s2_kernel(
    const float* __restrict__ adj, const float* __restrict__ ps,
    const float* __restrict__ pss, const float* __restrict__ query,
    const float* __restrict__ Wg1, const float* __restrict__ Wf1,
    const float* __restrict__ Wf2, const float* __restrict__ Wo1,
    const float* __restrict__ Wo2, const float* __restrict__ Wg2,
    const float* __restrict__ Wo, const float* __restrict__ bg2,
    const float* __restrict__ bo1, const float* __restrict__ bo2,
    unsigned short* __restrict__ anh, unsigned short* __restrict__ anl,
    unsigned short* __restrict__ Yfh, unsigned short* __restrict__ Yfl,
    unsigned short* __restrict__ Wf1f, unsigned short* __restrict__ Wf2f,
    unsigned short* __restrict__ Wo1f, unsigned short* __restrict__ Wg2hf,
    unsigned short* __restrict__ Wg2lf, unsigned short* __restrict__ W32hf,
    unsigned short* __restrict__ W32lf, unsigned short* __restrict__ Wof,
    float* __restrict__ c2, const unsigned short* __restrict__ qh,
    const unsigned short* __restrict__ kh, const unsigned short* __restrict__ vt,
    unsigned short* __restrict__ obf) {
  __shared__ float r1[4], r2[4];
  __shared__ __align__(16) char smem[33280];
  const int tid = threadIdx.x, b = blockIdx.x;
  if (b < 900) {
    float* pool = (float*)smem;
    if (b < 256) {
      float s = ps[tid] + ps[tid + 256];
      float ss = pss[tid] + pss[tid + 256];
      s = wave_sum(s);
      ss = wave_sum(ss);
      if ((tid & 63) == 0) { r1[tid >> 6] = s; r2[tid >> 6] = ss; }
      __syncthreads();
      const float sum = r1[0] + r1[1] + r1[2] + r1[3];
      const float sqs = r2[0] + r2[1] + r2[2] + r2[3];
      const float am = sum * (1.f / 262144.f);
      const float var = sqs * (1.f / 262144.f) - am * am;
      const float rs = rsqrtf(var + LN_EPS);
      const int i = (b * 256 + tid) * 4;
      float4 v = *(const float4*)&adj[i];
      float vals[4] = {(v.x - am) * rs, (v.y - am) * rs, (v.z - am) * rs,
                       (v.w - am) * rs};
      unsigned short th4[4], tl4[4];
#pragma unroll
      for (int j = 0; j < 4; ++j) {
        th4[j] = f2b(vals[j]);
        tl4[j] = f2b(vals[j] - b2f(th4[j]));
      }
      *(short4v*)&anh[i] = *(short4v*)th4;
      *(short4v*)&anl[i] = *(short4v*)tl4;
    } else if (b < 320) {
      const int id = (b - 256) * 256 + tid;
      const int n = id >> 6, k = id & 63;
      Wf1f[((k >> 4) * 256 + n) * 16 + (k & 15)] = f2b(Wf1[id]);
    } else if (b < 384) {
      const int id = (b - 320) * 256 + tid;
      const int n = id >> 8, k = id & 255;
      Wf2f[((k >> 4) * 64 + n) * 16 + (k & 15)] = f2b(Wf2[id]);
    } else if (b < 896) {
      const int pb = b - 384;
      const int w = tid >> 6, lane = tid & 63;
      const int mt = pb & 31;
      const int t = (pb >> 5) * 4 + w;
      float* xs = pool;
      float* Ls = pool + 256;
      float wc[64];
#pragma unroll
      for (int e = 0; e < 16; ++e)
        *(float4*)&wc[e * 4] = *(const float4*)&Wg1[lane * 64 + e * 4];
#pragma unroll 4
      for (int ms = 0; ms < 16; ++ms) {
        const int r = (mt * 16 + ms) * 64 + t;
        xs[w * 64 + lane] = query[r * 64 + lane];
        float acc = 0.f;
#pragma unroll
        for (int e = 0; e < 64; ++e) acc = fmaf(xs[w * 64 + e], wc[e], acc);
        Ls[(w * 16 + ms) * 68 + lane] = acc;
      }
      unsigned int dh[8], dl[8];
#pragma unroll
      for (int j = 0; j < 8; ++j) {
        float v0 = Ls[(w * 16 + 2 * j) * 68 + lane];
        float v1 = Ls[(w * 16 + 2 * j + 1) * 68 + lane];
        unsigned int h0 = f2b(v0), h1 = f2b(v1);
        unsigned int l0 = f2b(v0 - b2f((unsigned short)h0));
        unsigned int l1 = f2b(v1 - b2f((unsigned short)h1));
        dh[j] = h0 | (h1 << 16);
        dl[j] = l0 | (l1 << 16);
      }
      const int off = ((mt * 4096) + t * 64 + lane) * 16;
      *(uint4*)(Yfh + off) = *(uint4*)&dh[0];
      *(uint4*)(Yfh + off + 8) = *(uint4*)&dh[4];
      *(uint4*)(Yfl + off) = *(uint4*)&dl[0];
      *(uint4*)(Yfl + off + 8) = *(uint4*)&dl[4];
    } else if (b == 896) {
      for (int i = tid; i < 4096; i += 256) {
        const int n = i >> 6, k = i & 63;
        Wo1f[((k >> 4) * 64 + n) * 16 + (k & 15)] = f2b(Wo1[i]);
      }
    } else if (b == 897) {
      for (int i = tid; i < 4096; i += 256) {
        const int n = i >> 6, k = i & 63;
        const float v = Wg2[i];
        const unsigned short h = f2b(v);
        const unsigned short l = f2b(v - b2f(h));
        Wg2hf[((k >> 4) * 64 + n) * 16 + (k & 15)] = h;
        Wg2lf[((k >> 4) * 64 + n) * 16 + (k & 15)] = l;
      }
    } else if (b == 898) {
      float* wo2s = pool;
      float* wg2s = pool + 4096;
      float* bg2s = pool + 8192;
      for (int i = tid; i < 4096; i += 256) {
        wo2s[i] = Wo2[i];
        wg2s[i] = Wg2[i];
      }
      if (tid < 64) bg2s[tid] = bg2[tid];
      __syncthreads();
#pragma unroll 4
      for (int t = 0; t < 16; ++t) {
        const int i = t * 256 + tid;
        const int r = i >> 6, c = i & 63;
        float acc = 0.f;
#pragma unroll
        for (int e = 0; e < 64; ++e)
          acc = fmaf(wo2s[r * 64 + e], wg2s[e * 64 + c], acc);
        const unsigned short h = f2b(acc);
        const unsigned short l = f2b(acc - b2f(h));
        W32hf[((c >> 4) * 64 + r) * 16 + (c & 15)] = h;
        W32lf[((c >> 4) * 64 + r) * 16 + (c & 15)] = l;
      }
      if (tid < 64) {
        float acc = bo1[tid] + bo2[tid];
#pragma unroll
        for (int e = 0; e < 64; ++e)
          acc = fmaf(wo2s[tid * 64 + e], bg2s[e], acc);
        c2[tid] = acc;
      }
    } else {
      for (int i = tid; i < 4096; i += 256) {
        const int n = i >> 6, k = i & 63;
        Wof[((k >> 4) * 64 + n) * 16 + (k & 15)] = f2b(Wo[i]);
      }
    }
  } else {
    // ---- attention block
    unsigned short* Vs = (unsigned short*)smem;
    const int bx = b - 900;
    const int th = bx >> 2;
    {
      const unsigned short* vb = vt + th * 8192;
#pragma unroll
      for (int it = 0; it < 4; ++it) {
        const int flat = (it * 256 + tid) * 8;
        const int d = flat >> 9, k = flat & 511;
        *(int4*)&Vs[d * VPAD + k] = *(const int4*)&vb[flat];
      }
    }
    __syncthreads();

    const int lane = tid & 15;
    const int quad = (tid >> 4) & 3;
    const int w = tid >> 6;
    const int q0 = (bx & 3) * 128 + w * 32;

    const unsigned short* qbase = qh + th * 8192;
    const unsigned short* kbase = kh + th * 8192;
    short4v qf[2];
#pragma unroll
    for (int ct = 0; ct < 2; ++ct)
      qf[ct] = *(const short4v*)&qbase[(q0 + ct * 16 + lane) * 16 + quad * 4];

    float4v acc[2];
    float l[2];
#pragma unroll
    for (int ct = 0; ct < 2; ++ct) {
      acc[ct].x = 0.f; acc[ct].y = 0.f; acc[ct].z = 0.f; acc[ct].w = 0.f;
      l[ct] = 0.f;
    }
    float4v zero;
    zero.x = 0.f; zero.y = 0.f; zero.z = 0.f; zero.w = 0.f;

    const unsigned short* vrow = &Vs[lane * VPAD];

    for (int kt = 0; kt < 32; ++kt) {
      const short4v kf =
          *(const short4v*)&kbase[(kt * 16 + lane) * 16 + quad * 4];
      const short4v vf = *(const short4v*)&vrow[kt * 16 + quad * 4];
#pragma unroll
      for (int ct = 0; ct < 2; ++ct) {
        float4v s = mfma_16x16x16_bf16(kf, qf[ct], zero);
        float p0 = __expf(s.x);
        float p1 = __expf(s.y);
        float p2 = __expf(s.z);
        float p3 = __expf(s.w);
        l[ct] += (p0 + p1) + (p2 + p3);
        unsigned int u0 = __float_as_uint(p0) + 0x8000u;
        unsigned int u1 = __float_as_uint(p1) + 0x8000u;
        unsigned int u2 = __float_as_uint(p2) + 0x8000u;
        unsigned int u3 = __float_as_uint(p3) + 0x8000u;
        union {
          uint2 u;
          short4v s4;
        } pk;
        pk.u.x = __builtin_amdgcn_perm(u1, u0, 0x07060302u);
        pk.u.y = __builtin_amdgcn_perm(u3, u2, 0x07060302u);
        acc[ct] = mfma_16x16x16_bf16(vf, pk.s4, acc[ct]);
      }
    }

    const int t = th >> 2, h = th & 3;
#pragma unroll
    for (int ct = 0; ct < 2; ++ct) {
      float lt = l[ct];
      lt += __shfl_xor(lt, 16, 64);
      lt += __shfl_xor(lt, 32, 64);
      const float inv = 1.f / lt;
      unsigned short tmp[4];
      tmp[0] = f2b(acc[ct].x * inv);
      tmp[1] = f2b(acc[ct].y * inv);
      tmp[2] = f2b(acc[ct].z * inv);
      tmp[3] = f2b(acc[ct].w * inv);
      const int q = q0 + ct * 16 + lane;
      *(uint2*)&obf[(q * 64 + t) * 64 + h * 16 + quad * 4] = *(uint2*)tmp;
    }
  }
}

// ---------------------------------------------------------------------------
// S3: xffn (blocks 0..511, all-MFMA, 42KB LDS)  U  gcn_gemm1 (blocks
// 512..1023, zero-LDS, wave tile 32x32, 3 independent acc sets per tile).
// ---------------------------------------------------------------------------
__global__ __launch_bounds__(256) void s3_kernel(
    const unsigned short* __restrict__ obf, const float* __restrict__ query,
    const unsigned short* __restrict__ Wof, const float* __restrict__ bo,
    const float* __restrict__ g1, const float* __restrict__ b1,
    const unsigned short* __restrict__ Wf1f, const float* __restrict__ bf1,
    const unsigned short* __restrict__ Wf2f, const float* __restrict__ bf2,
    const float* __restrict__ g2, const float* __restrict__ b2,
    float* __restrict__ out1, unsigned short* __restrict__ out1b,
    const unsigned short* __restrict__ Ah, const unsigned short* __restrict__ Al,
    const unsigned short* __restrict__ Bh, const unsigned short* __restrict__ Bl,
    const float* __restrict__ bg1, unsigned short* __restrict__ Hh,
    unsigned short* __restrict__ Hl) {
  __shared__ __align__(16) char smem[41984];
  const int tid = threadIdx.x, b = blockIdx.x;
  const int w = tid >> 6, lane = tid & 63;
  const int ln = lane & 15, quad = lane >> 4;
  if (b < 512) {
    unsigned short* xb = (unsigned short*)smem;            // [64*68]
    unsigned short* hid = (unsigned short*)(smem + 8704);  // [64*260]
    const int n = b;
    float xres[4][4];

    // ---- Phase A: x = LN1(obf @ Wo^T + bo + query), MFMA
    {
      const unsigned short* ap = obf + (n * 64 + w * 16 + ln) * 64 + quad * 4;
      float4v acc[4];
#pragma unroll
      for (int j = 0; j < 4; ++j) {
        acc[j].x = 0.f; acc[j].y = 0.f; acc[j].z = 0.f; acc[j].w = 0.f;
      }
#pragma unroll
      for (int kt = 0; kt < 4; ++kt) {
        const short4v a = *(const short4v*)(ap + kt * 16);
#pragma unroll
        for (int j = 0; j < 4; ++j) {
          const short4v bfr =
              *(const short4v*)&Wof[(kt * 64 + j * 16 + ln) * 16 + quad * 4];
          acc[j] = mfma_16x16x16_bf16(a, bfr, acc[j]);
        }
      }
#pragma unroll
      for (int reg = 0; reg < 4; ++reg) {
        const int row = w * 16 + quad * 4 + reg;
        float v[4];
        float s = 0.f;
#pragma unroll
        for (int j = 0; j < 4; ++j) {
          const int col = j * 16 + ln;
          v[j] = acc[j][reg] + bo[col] + query[(n * 64 + row) * 64 + col];
          s += v[j];
        }
        s += __shfl_xor(s, 1, 64);
        s += __shfl_xor(s, 2, 64);
        s += __shfl_xor(s, 4, 64);
        s += __shfl_xor(s, 8, 64);
        const float mean = s * 0.015625f;
        float vv = 0.f;
#pragma unroll
        for (int j = 0; j < 4; ++j) {
          const float dd = v[j] - mean;
          vv += dd * dd;
        }
        vv += __shfl_xor(vv, 1, 64);
        vv += __shfl_xor(vv, 2, 64);
        vv += __shfl_xor(vv, 4, 64);
        vv += __shfl_xor(vv, 8, 64);
        const float rs = rsqrtf(vv * 0.015625f + LN_EPS);
#pragma unroll
        for (int j = 0; j < 4; ++j) {
          const int col = j * 16 + ln;
          const float xv = (v[j] - mean) * rs * g1[col] + b1[col];
          xres[j][reg] = xv;
          xb[row * 68 + col] = f2b(xv);
        }
      }
    }
    __syncthreads();

    // ---- Phase B: hid = relu(x @ Wf1^T + bf1)
    {
      const int wm = (w & 1) * 32, wn = (w >> 1) * 128;
      float4v acc[2][8];
#pragma unroll
      for (int i = 0; i < 2; ++i)
#pragma unroll
        for (int j = 0; j < 8; ++j) {
          acc[i][j].x = 0.f; acc[i][j].y = 0.f;
          acc[i][j].z = 0.f; acc[i][j].w = 0.f;
        }
#pragma unroll
      for (int kt = 0; kt < 4; ++kt) {
        short4v a0 = *(const short4v*)&xb[(wm + ln) * 68 + kt * 16 + quad * 4];
        short4v a1 =
            *(const short4v*)&xb[(wm + 16 + ln) * 68 + kt * 16 + quad * 4];
#pragma unroll
        for (int j = 0; j < 8; ++j) {
          short4v bfr = *(const short4v*)&Wf1f[(kt * 256 + wn + j * 16 + ln) *
                                                   16 + quad * 4];
          acc[0][j] = mfma_16x16x16_bf16(a0, bfr, acc[0][j]);
          acc[1][j] = mfma_16x16x16_bf16(a1, bfr, acc[1][j]);
        }
      }
#pragma unroll
      for (int mt = 0; mt < 2; ++mt)
#pragma unroll
        for (int j = 0; j < 8; ++j) {
          const int col = wn + j * 16 + ln;
          const float bb = bf1[col];
#pragma unroll
          for (int reg = 0; reg < 4; ++reg) {
            const int row = wm + mt * 16 + quad * 4 + reg;
            hid[row * 260 + col] = f2b(fmaxf(acc[mt][j][reg] + bb, 0.f));
          }
        }
    }
    __syncthreads();

    // ---- Phase C: out1 = LN2(hid @ Wf2^T + bf2 + x)
    {
      float4v acc[4];
#pragma unroll
      for (int j = 0; j < 4; ++j) {
        acc[j].x = 0.f; acc[j].y = 0.f; acc[j].z = 0.f; acc[j].w = 0.f;
      }
#pragma unroll 4
      for (int kt = 0; kt < 16; ++kt) {
        short4v a =
            *(const short4v*)&hid[(w * 16 + ln) * 260 + kt * 16 + quad * 4];
#pragma unroll
        for (int j = 0; j < 4; ++j) {
          short4v bfr =
              *(const short4v*)&Wf2f[(kt * 64 + j * 16 + ln) * 16 + quad * 4];
          acc[j] = mfma_16x16x16_bf16(a, bfr, acc[j]);
        }
      }
#pragma unroll
      for (int reg = 0; reg < 4; ++reg) {
        const int row = w * 16 + quad * 4 + reg;
        float v[4];
        float s = 0.f;
#pragma unroll
        for (int j = 0; j < 4; ++j) {
          v[j] = acc[j][reg] + bf2[j * 16 + ln] + xres[j][reg];
          s += v[j];
        }
        s += __shfl_xor(s, 1, 64);
        s += __shfl_xor(s, 2, 64);
        s += __shfl_xor(s, 4, 64);
        s += __shfl_xor(s, 8, 64);
        const float mean = s * 0.015625f;
        float vv = 0.f;
#pragma unroll
        for (int j = 0; j < 4; ++j) {
          const float dd = v[j] - mean;
          vv += dd * dd;
        }
        vv += __shfl_xor(vv, 1, 64);
        vv += __shfl_xor(vv, 2, 64);
        vv += __shfl_xor(vv, 4, 64);
        vv += __shfl_xor(vv, 8, 64);
        const float rs = rsqrtf(vv * 0.015625f + LN_EPS);
#pragma unroll
        for (int j = 0; j < 4; ++j) {
          const float ov =
              (v[j] - mean) * rs * g2[j * 16 + ln] + b2[j * 16 + ln];
          const int idx = (n * 64 + row) * 64 + j * 16 + ln;
          out1[idx] = ov;
          out1b[idx] = f2b(ov);
        }
      }
    }
  } else {
    // ---- gcn_gemm1 block (zero LDS), wave tile 32x32, independent accs
    const int pb = b - 512;  // 0..511
    const int m0 = (pb >> 6) * 64 + (w & 1) * 32;
    const int n0 = (pb & 63) * 64 + (w >> 1) * 32;

    const unsigned short* ah0 = Ah + (m0 + ln) * 512 + quad * 4;
    const unsigned short* al0 = Al + (m0 + ln) * 512 + quad * 4;
    const unsigned short* bh0 = Bh + (n0 + ln) * 16 + quad * 4;
    const unsigned short* bl0 = Bl + (n0 + ln) * 16 + quad * 4;

    float4v ahh[2][2], ahl[2][2], alh[2][2];
#pragma unroll
    for (int i = 0; i < 2; ++i)
#pragma unroll
      for (int j = 0; j < 2; ++j) {
        ahh[i][j].x = 0.f; ahh[i][j].y = 0.f; ahh[i][j].z = 0.f; ahh[i][j].w = 0.f;
        ahl[i][j] = ahh[i][j];
        alh[i][j] = ahh[i][j];
      }

#pragma unroll 4
    for (int kt = 0; kt < 32; ++kt) {
      short4v a0h = *(const short4v*)(ah0 + kt * 16);
      short4v a1h = *(const short4v*)(ah0 + 16 * 512 + kt * 16);
      short4v a0l = *(const short4v*)(al0 + kt * 16);
      short4v a1l = *(const short4v*)(al0 + 16 * 512 + kt * 16);
#pragma unroll
      for (int j = 0; j < 2; ++j) {
        const int boff = (kt * 4096 + j * 16) * 16;
        short4v bh = *(const short4v*)(bh0 + boff);
        short4v bl = *(const short4v*)(bl0 + boff);
        ahh[0][j] = mfma_16x16x16_bf16(a0h, bh, ahh[0][j]);
        ahl[0][j] = mfma_16x16x16_bf16(a0h, bl, ahl[0][j]);
        alh[0][j] = mfma_16x16x16_bf16(a0l, bh, alh[0][j]);
        ahh[1][j] = mfma_16x16x16_bf16(a1h, bh, ahh[1][j]);
        ahl[1][j] = mfma_16x16x16_bf16(a1h, bl, ahl[1][j]);
        alh[1][j] = mfma_16x16x16_bf16(a1l, bh, alh[1][j]);
      }
    }

#pragma unroll
    for (int mt = 0; mt < 2; ++mt) {
      const int mtile = (m0 + mt * 16) >> 4;
#pragma unroll
      for (int j = 0; j < 2; ++j) {
        const int col = n0 + j * 16 + ln;
        const float bb = bg1[col & 63];
        unsigned short hh[4], hl[4];
#pragma unroll
        for (int reg = 0; reg < 4; ++reg) {
          float v = fmaxf(
              ahh[mt][j][reg] + ahl[mt][j][reg] + alh[mt][j][reg] + bb, 0.f);
          hh[reg] = f2b(v);
          hl[reg] = f2b(v - b2f(hh[reg]));
        }
        const int off = (mtile * 4096 + col) * 16 + quad * 4;
        *(uint2*)&Hh[off] = *(uint2*)hh;
        *(uint2*)&Hl[off] = *(uint2*)hl;
      }
    }
  }
}

// ---------------------------------------------------------------------------
// S4: split GEMM2: G2 = adj_n @ Hr -> split bf16. 1024 blocks (4/CU),
// wave tile 16m x 32n, 3 independent acc sets (6 independent MFMA chains).
// ---------------------------------------------------------------------------
__global__ __launch_bounds__(256) void s4_kernel(
    const unsigned short* __restrict__ Ah, const unsigned short* __restrict__ Al,
    const unsigned short* __restrict__ Bh, const unsigned short* __restrict__ Bl,
    unsigned short* __restrict__ G2h, unsigned short* __restrict__ G2l) {
  const int tid = threadIdx.x;
  const int wave = tid >> 6, lane = tid & 63;
  const int ln = lane & 15, quad = lane >> 4;
  const int m0 = (blockIdx.x >> 6) * 32 + (wave & 1) * 16;
  const int n0 = (blockIdx.x & 63) * 64 + (wave >> 1) * 32;

  const unsigned short* ah0 = Ah + (m0 + ln) * 512 + quad * 4;
  const unsigned short* al0 = Al + (m0 + ln) * 512 + quad * 4;
  const unsigned short* bh0 = Bh + (n0 + ln) * 16 + quad * 4;
  const unsigned short* bl0 = Bl + (n0 + ln) * 16 + quad * 4;

  float4v ahh[2], ahl[2], alh[2];
#pragma unroll
  for (int j = 0; j < 2; ++j) {
    ahh[j].x = 0.f; ahh[j].y = 0.f; ahh[j].z = 0.f; ahh[j].w = 0.f;
    ahl[j] = ahh[j];
    alh[j] = ahh[j];
  }

#pragma unroll 4
  for (int kt = 0; kt < 32; ++kt) {
    short4v ah = *(const short4v*)(ah0 + kt * 16);
    short4v al = *(const short4v*)(al0 + kt * 16);
#pragma unroll
    for (int j = 0; j < 2; ++j) {
      const int boff = (kt * 4096 + j * 16) * 16;
      short4v bh = *(const short4v*)(bh0 + boff);
      short4v bl = *(const short4v*)(bl0 + boff);
      ahh[j] = mfma_16x16x16_bf16(ah, bh, ahh[j]);
      ahl[j] = mfma_16x16x16_bf16(ah, bl, ahl[j]);
      alh[j] = mfma_16x16x16_bf16(al, bh, alh[j]);
    }
  }

#pragma unroll
  for (int j = 0; j < 2; ++j) {
    const int col = n0 + j * 16 + ln;
#pragma unroll
    for (int reg = 0; reg < 4; ++reg) {
      const int row = m0 + quad * 4 + reg;
      const float v = ahh[j][reg] + ahl[j][reg] + alh[j][reg];
      const unsigned short h = f2b(v);
      G2h[row * 4096 + col] = h;
      G2l[row * 4096 + col] = f2b(v - b2f(h));
    }
  }
}

// ---------------------------------------------------------------------------
// S5: MFMA gate (verified R7).
// ---------------------------------------------------------------------------
__global__ __launch_bounds__(256) void s5_kernel(
    const unsigned short* __restrict__ out1b, const float* __restrict__ out1,
    const unsigned short* __restrict__ G2h, const unsigned short* __restrict__ G2l,
    const unsigned short* __restrict__ Wo1f, const unsigned short* __restrict__ Wg2hf,
    const unsigned short* __restrict__ Wg2lf, const unsigned short* __restrict__ W32hf,
    const unsigned short* __restrict__ W32lf, const float* __restrict__ bg2,
    const float* __restrict__ c2, float* __restrict__ dst) {
  const int tid = threadIdx.x;
  const int wave = tid >> 6, lane = tid & 63;
  const int ln = lane & 15, quad = lane >> 4;
  const int m0 = blockIdx.x * 64 + wave * 16;

  const unsigned short* o1p = out1b + (m0 + ln) * 64 + quad * 4;
  const unsigned short* ghp = G2h + (m0 + ln) * 64 + quad * 4;
  const unsigned short* glp = G2l + (m0 + ln) * 64 + quad * 4;

  float4v aco[4], aca[4];
#pragma unroll
  for (int j = 0; j < 4; ++j) {
    aco[j].x = 0.f; aco[j].y = 0.f; aco[j].z = 0.f; aco[j].w = 0.f;
    aca[j].x = 0.f; aca[j].y = 0.f; aca[j].z = 0.f; aca[j].w = 0.f;
  }

#pragma unroll
  for (int kt = 0; kt < 4; ++kt) {
    const short4v ao = *(const short4v*)(o1p + kt * 16);
    const short4v gh = *(const short4v*)(ghp + kt * 16);
    const short4v gl = *(const short4v*)(glp + kt * 16);
#pragma unroll
    for (int j = 0; j < 4; ++j) {
      const int boff = (kt * 64 + j * 16 + ln) * 16 + quad * 4;
      const short4v wgh = *(const short4v*)(Wg2hf + boff);
      const short4v wgl = *(const short4v*)(Wg2lf + boff);
      const short4v wo1 = *(const short4v*)(Wo1f + boff);
      const short4v w3h = *(const short4v*)(W32hf + boff);
      const short4v w3l = *(const short4v*)(W32lf + boff);
      aco[j] = mfma_16x16x16_bf16(gl, wgh, aco[j]);
      aco[j] = mfma_16x16x16_bf16(gh, wgl, aco[j]);
      aco[j] = mfma_16x16x16_bf16(gh, wgh, aco[j]);
      aca[j] = mfma_16x16x16_bf16(ao, wo1, aca[j]);
      aca[j] = mfma_16x16x16_bf16(gl, w3h, aca[j]);
      aca[j] = mfma_16x16x16_bf16(gh, w3l, aca[j]);
      aca[j] = mfma_16x16x16_bf16(gh, w3h, aca[j]);
    }
  }

#pragma unroll
  for (int j = 0; j < 4; ++j) {
    const int col = j * 16 + ln;
    const float bg2v = bg2[col];
    const float c2v = c2[col];
#pragma unroll
    for (int reg = 0; reg < 4; ++reg) {
      const int row = m0 + quad * 4 + reg;
      const float o2 = aco[j][reg] + bg2v;
      const float a = aca[j][reg] + c2v;
      const float o1v = out1[row * 64 + col];
      const float g = 1.f / (1.f + __expf(-a));
      dst[row * 64 + col] = o2 + g * (o1v - o2);
    }
  }
}

// ---------------------------------------------------------------------------
extern "C" void kernel_launch(void* const* d_in, const int* in_sizes, int n_in,
                              void* d_out, int out_size, void* d_ws,
                              size_t ws_size, hipStream_t stream) {
  const float* value = (const float*)d_in[0];
  const float* key_t = (const float*)d_in[1];
  const float* query = (const float*)d_in[2];
  const float* adj = (const float*)d_in[3];
  const float* Wv = (const float*)d_in[4];
  const float* Wk = (const float*)d_in[5];
  const float* Wq = (const float*)d_in[6];
  const float* Wo = (const float*)d_in[7];
  const float* bo = (const float*)d_in[8];
  const float* g1 = (const float*)d_in[9];
  const float* b1 = (const float*)d_in[10];
  const float* g2 = (const float*)d_in[11];
  const float* b2 = (const float*)d_in[12];
  const float* Wf1 = (const float*)d_in[13];
  const float* bf1 = (const float*)d_in[14];
  const float* Wf2 = (const float*)d_in[15];
  const float* bf2 = (const float*)d_in[16];
  const float* Wg1 = (const float*)d_in[17];
  const float* bg1 = (const float*)d_in[18];
  const float* Wg2 = (const float*)d_in[19];
  const float* bg2 = (const float*)d_in[20];
  const float* Wo1 = (const float*)d_in[21];
  const float* bo1 = (const float*)d_in[22];
  const float* Wo2 = (const float*)d_in[23];
  const float* bo2 = (const float*)d_in[24];

  float* ws = (float*)d_ws;
  const size_t M1 = 1048576;
  unsigned short* obf = (unsigned short*)(ws + 0);          // [0,1M) bf16
  float* out1 = ws + 2 * M1;                                // [2M,4M)
  unsigned short* out1b = (unsigned short*)(ws + 4 * M1);   // [4M,5M)
  unsigned short* qh = (unsigned short*)(ws + 5 * M1);
  unsigned short* kh = (unsigned short*)(ws + 6 * M1);
  unsigned short* vt = (unsigned short*)(ws + 7 * M1);
  unsigned short* Yfh = (unsigned short*)(ws + 8 * M1);
  unsigned short* Yfl = (unsigned short*)(ws + 9 * M1);
  unsigned short* Hrfh = (unsigned short*)(ws + 10 * M1);
  unsigned short* Hrfl = (unsigned short*)(ws + 11 * M1);
  unsigned short* G2h = (unsigned short*)(ws + 12 * M1);
  unsigned short* G2l = (unsigned short*)(ws + 13 * M1);
  unsigned short* anh = (unsigned short*)(ws + 14 * M1);
  unsigned short* anl = (unsigned short*)(ws + 14 * M1 + 131072);
  float* wbase = ws + 14 * M1 + 262144;
  unsigned short* Wf1f = (unsigned short*)(wbase);
  unsigned short* Wf2f = (unsigned short*)(wbase + 8192);
  unsigned short* Wo1f = (unsigned short*)(wbase + 16384);
  unsigned short* Wg2hf = (unsigned short*)(wbase + 18432);
  unsigned short* Wg2lf = (unsigned short*)(wbase + 20480);
  unsigned short* W32hf = (unsigned short*)(wbase + 22528);
  unsigned short* W32lf = (unsigned short*)(wbase + 24576);
  unsigned short* Wof = (unsigned short*)(wbase + 26624);
  float* c2 = wbase + 28672;
  float* ps = wbase + 28736;
  float* pss = ps + 512;
  float* dst = (float*)d_out;

  s1_kernel<<<768, 256, 0, stream>>>(adj, ps, pss, value, key_t, query, Wv,
                                     Wk, Wq, vt, kh, qh);
  s2_kernel<<<1924, 256, 0, stream>>>(adj, ps, pss, query, Wg1, Wf1, Wf2, Wo1,
                                      Wo2, Wg2, Wo, bg2, bo1, bo2, anh, anl,
                                      Yfh, Yfl, Wf1f, Wf2f, Wo1f, Wg2hf,
                                      Wg2lf, W32hf, W32lf, Wof, c2, qh, kh,
                                      vt, obf);
  s3_kernel<<<1024, 256, 0, stream>>>(obf, query, Wof, bo, g1, b1, Wf1f, bf1,
                                      Wf2f, bf2, g2, b2, out1, out1b, anh, anl,
                                      Yfh, Yfl, bg1, Hrfh, Hrfl);
  s4_kernel<<<1024, 256, 0, stream>>>(anh, anl, Hrfh, Hrfl, G2h, G2l);
  s5_kernel<<<512, 256, 0, stream>>>(out1b, out1, G2h, G2l, Wo1f, Wg2hf,
                                     Wg2lf, W32hf, W32lf, bg2, c2, dst);
}

// Round 11
// 246.804 us; speedup vs baseline: 1.1058x; 1.1058x over previous
//
#include <hip/hip_runtime.h>

#define LN_EPS 1e-5f

typedef __attribute__((ext_vector_type(4))) short short4v;
typedef __attribute__((ext_vector_type(4))) float float4v;

__device__ __forceinline__ float wave_sum(float v) {
#pragma unroll
  for (int o = 32; o > 0; o >>= 1) v += __shfl_xor(v, o, 64);
  return v;
}

__device__ __forceinline__ unsigned short f2b(float f) {
  unsigned int u = __float_as_uint(f);
  u += 0x7fffu + ((u >> 16) & 1u);
  return (unsigned short)(u >> 16);
}

__device__ __forceinline__ float b2f(unsigned short h) {
  return __uint_as_float(((unsigned int)h) << 16);
}

__device__ __forceinline__ float4v mfma_16x16x16_bf16(short4v a, short4v b,
                                                      float4v c) {
#if __has_builtin(__builtin_amdgcn_mfma_f32_16x16x16bf16_1k)
  return __builtin_amdgcn_mfma_f32_16x16x16bf16_1k(a, b, c, 0, 0, 0);
#else
  float4v d;
  asm volatile(
      "v_mfma_f32_16x16x16_bf16 %0, %1, %2, %3\n\ts_nop 7\n\ts_nop 7"
      : "=v"(d)
      : "v"(a), "v"(b), "v"(c));
  return d;
#endif
}

// ---------------------------------------------------------------------------
// S1: adj_part (blocks 0..511)  U  qkv projection (blocks 512..767).
// ---------------------------------------------------------------------------
__global__ __launch_bounds__(256) void s1_kernel(
    const float* __restrict__ adj, float* __restrict__ ps,
    float* __restrict__ pss, const float* __restrict__ value,
    const float* __restrict__ keyt, const float* __restrict__ query,
    const float* __restrict__ Wv, const float* __restrict__ Wk,
    const float* __restrict__ Wq, unsigned short* __restrict__ vt,
    unsigned short* __restrict__ kh, unsigned short* __restrict__ qh) {
  __shared__ float r1[4], r2[4];
  __shared__ __align__(16) float wv[256], wk[256], wq[256];
  const int b = blockIdx.x, tid = threadIdx.x;
  if (b < 512) {
    float v0 = adj[b * 512 + tid], v1 = adj[b * 512 + 256 + tid];
    float s = v0 + v1;
    float ss = fmaf(v0, v0, v1 * v1);
    s = wave_sum(s);
    ss = wave_sum(ss);
    if ((tid & 63) == 0) { r1[tid >> 6] = s; r2[tid >> 6] = ss; }
    __syncthreads();
    if (tid == 0) {
      ps[b] = r1[0] + r1[1] + r1[2] + r1[3];
      pss[b] = r2[0] + r2[1] + r2[2] + r2[3];
    }
  } else {
    wv[tid] = Wv[tid];
    wk[tid] = Wk[tid];
    wq[tid] = Wq[tid] * 0.125f;
    __syncthreads();
    const int th = b - 512;
    const int t = th >> 2, h = th & 3;
    const int base = t * 64 + h * 16;
    float y[16];
    unsigned short tmp[16];

#define XFORM(SRC, WARR)                                            \
  {                                                                 \
    const float4* p = (const float4*)(SRC + n * 4096 + base);       \
    float x[16];                                                    \
    *(float4*)(x + 0) = p[0];                                       \
    *(float4*)(x + 4) = p[1];                                       \
    *(float4*)(x + 8) = p[2];                                       \
    *(float4*)(x + 12) = p[3];                                      \
    _Pragma("unroll") for (int d = 0; d < 16; ++d) {                \
      float acc = 0.f;                                              \
      _Pragma("unroll") for (int e4 = 0; e4 < 4; ++e4) {            \
        float4 w4 = *(const float4*)&WARR[d * 16 + e4 * 4];         \
        acc = fmaf(w4.x, x[e4 * 4 + 0], acc);                       \
        acc = fmaf(w4.y, x[e4 * 4 + 1], acc);                       \
        acc = fmaf(w4.z, x[e4 * 4 + 2], acc);                       \
        acc = fmaf(w4.w, x[e4 * 4 + 3], acc);                       \
      }                                                             \
      y[d] = acc;                                                   \
    }                                                               \
  }

    for (int s = 0; s < 2; ++s) {
      const int n = tid + (s << 8);
      XFORM(value, wv)
#pragma unroll
      for (int d = 0; d < 16; ++d) vt[th * 8192 + d * 512 + n] = f2b(y[d]);
      XFORM(keyt, wk)
#pragma unroll
      for (int d = 0; d < 16; ++d) tmp[d] = f2b(y[d]);
      *(int4*)&kh[(th * 512 + n) * 16] = *(int4*)&tmp[0];
      *(int4*)&kh[(th * 512 + n) * 16 + 8] = *(int4*)&tmp[8];
      XFORM(query, wq)
#pragma unroll
      for (int d = 0; d < 16; ++d) tmp[d] = f2b(y[d]);
      *(int4*)&qh[(th * 512 + n) * 16] = *(int4*)&tmp[0];
      *(int4*)&qh[(th * 512 + n) * 16 + 8] = *(int4*)&tmp[8];
    }
#undef XFORM
  }
}

// ---------------------------------------------------------------------------
// S2: prep (blocks 0..899)  U  MFMA attention (blocks 900..1923).
// ---------------------------------------------------------------------------
#define VPAD 536
__global__ __launch_bounds__(256) void s2_kernel(
    const float* __restrict__ adj, const float* __restrict__ ps,
    const float* __restrict__ pss, const float* __restrict__ query,
    const float* __restrict__ Wg1, const float* __restrict__ Wf1,
    const float* __restrict__ Wf2, const float* __restrict__ Wo1,
    const float* __restrict__ Wo2, const float* __restrict__ Wg2,
    const float* __restrict__ Wo, const float* __restrict__ bg2,
    const float* __restrict__ bo1, const float* __restrict__ bo2,
    unsigned short* __restrict__ anh, unsigned short* __restrict__ anl,
    unsigned short* __restrict__ Yfh, unsigned short* __restrict__ Yfl,
    unsigned short* __restrict__ Wf1f, unsigned short* __restrict__ Wf2f,
    unsigned short* __restrict__ Wo1f, unsigned short* __restrict__ Wg2hf,
    unsigned short* __restrict__ Wg2lf, unsigned short* __restrict__ W32hf,
    unsigned short* __restrict__ W32lf, unsigned short* __restrict__ Wof,
    float* __restrict__ c2, const unsigned short* __restrict__ qh,
    const unsigned short* __restrict__ kh, const unsigned short* __restrict__ vt,
    unsigned short* __restrict__ obf) {
  __shared__ float r1[4], r2[4];
  __shared__ __align__(16) char smem[33280];
  const int tid = threadIdx.x, b = blockIdx.x;
  if (b < 900) {
    float* pool = (float*)smem;
    if (b < 256) {
      float s = ps[tid] + ps[tid + 256];
      float ss = pss[tid] + pss[tid + 256];
      s = wave_sum(s);
      ss = wave_sum(ss);
      if ((tid & 63) == 0) { r1[tid >> 6] = s; r2[tid >> 6] = ss; }
      __syncthreads();
      const float sum = r1[0] + r1[1] + r1[2] + r1[3];
      const float sqs = r2[0] + r2[1] + r2[2] + r2[3];
      const float am = sum * (1.f / 262144.f);
      const float var = sqs * (1.f / 262144.f) - am * am;
      const float rs = rsqrtf(var + LN_EPS);
      const int i = (b * 256 + tid) * 4;
      float4 v = *(const float4*)&adj[i];
      float vals[4] = {(v.x - am) * rs, (v.y - am) * rs, (v.z - am) * rs,
                       (v.w - am) * rs};
      unsigned short th4[4], tl4[4];
#pragma unroll
      for (int j = 0; j < 4; ++j) {
        th4[j] = f2b(vals[j]);
        tl4[j] = f2b(vals[j] - b2f(th4[j]));
      }
      *(short4v*)&anh[i] = *(short4v*)th4;
      *(short4v*)&anl[i] = *(short4v*)tl4;
    } else if (b < 320) {
      const int id = (b - 256) * 256 + tid;
      const int n = id >> 6, k = id & 63;
      Wf1f[((k >> 4) * 256 + n) * 16 + (k & 15)] = f2b(Wf1[id]);
    } else if (b < 384) {
      const int id = (b - 320) * 256 + tid;
      const int n = id >> 8, k = id & 255;
      Wf2f[((k >> 4) * 64 + n) * 16 + (k & 15)] = f2b(Wf2[id]);
    } else if (b < 896) {
      const int pb = b - 384;
      const int w = tid >> 6, lane = tid & 63;
      const int mt = pb & 31;
      const int t = (pb >> 5) * 4 + w;
      float* xs = pool;
      float* Ls = pool + 256;
      float wc[64];
#pragma unroll
      for (int e = 0; e < 16; ++e)
        *(float4*)&wc[e * 4] = *(const float4*)&Wg1[lane * 64 + e * 4];
#pragma unroll 4
      for (int ms = 0; ms < 16; ++ms) {
        const int r = (mt * 16 + ms) * 64 + t;
        xs[w * 64 + lane] = query[r * 64 + lane];
        float acc = 0.f;
#pragma unroll
        for (int e = 0; e < 64; ++e) acc = fmaf(xs[w * 64 + e], wc[e], acc);
        Ls[(w * 16 + ms) * 68 + lane] = acc;
      }
      unsigned int dh[8], dl[8];
#pragma unroll
      for (int j = 0; j < 8; ++j) {
        float v0 = Ls[(w * 16 + 2 * j) * 68 + lane];
        float v1 = Ls[(w * 16 + 2 * j + 1) * 68 + lane];
        unsigned int h0 = f2b(v0), h1 = f2b(v1);
        unsigned int l0 = f2b(v0 - b2f((unsigned short)h0));
        unsigned int l1 = f2b(v1 - b2f((unsigned short)h1));
        dh[j] = h0 | (h1 << 16);
        dl[j] = l0 | (l1 << 16);
      }
      const int off = ((mt * 4096) + t * 64 + lane) * 16;
      *(uint4*)(Yfh + off) = *(uint4*)&dh[0];
      *(uint4*)(Yfh + off + 8) = *(uint4*)&dh[4];
      *(uint4*)(Yfl + off) = *(uint4*)&dl[0];
      *(uint4*)(Yfl + off + 8) = *(uint4*)&dl[4];
    } else if (b == 896) {
      for (int i = tid; i < 4096; i += 256) {
        const int n = i >> 6, k = i & 63;
        Wo1f[((k >> 4) * 64 + n) * 16 + (k & 15)] = f2b(Wo1[i]);
      }
    } else if (b == 897) {
      for (int i = tid; i < 4096; i += 256) {
        const int n = i >> 6, k = i & 63;
        const float v = Wg2[i];
        const unsigned short h = f2b(v);
        const unsigned short l = f2b(v - b2f(h));
        Wg2hf[((k >> 4) * 64 + n) * 16 + (k & 15)] = h;
        Wg2lf[((k >> 4) * 64 + n) * 16 + (k & 15)] = l;
      }
    } else if (b == 898) {
      float* wo2s = pool;
      float* wg2s = pool + 4096;
      float* bg2s = pool + 8192;
      for (int i = tid; i < 4096; i += 256) {
        wo2s[i] = Wo2[i];
        wg2s[i] = Wg2[i];
      }
      if (tid < 64) bg2s[tid] = bg2[tid];
      __syncthreads();
#pragma unroll 4
      for (int t = 0; t < 16; ++t) {
        const int i = t * 256 + tid;
        const int r = i >> 6, c = i & 63;
        float acc = 0.f;
#pragma unroll
        for (int e = 0; e < 64; ++e)
          acc = fmaf(wo2s[r * 64 + e], wg2s[e * 64 + c], acc);
        const unsigned short h = f2b(acc);
        const unsigned short l = f2b(acc - b2f(h));
        W32hf[((c >> 4) * 64 + r) * 16 + (c & 15)] = h;
        W32lf[((c >> 4) * 64 + r) * 16 + (c & 15)] = l;
      }
      if (tid < 64) {
        float acc = bo1[tid] + bo2[tid];
#pragma unroll
        for (int e = 0; e < 64; ++e)
          acc = fmaf(wo2s[tid * 64 + e], bg2s[e], acc);
        c2[tid] = acc;
      }
    } else {
      for (int i = tid; i < 4096; i += 256) {
        const int n = i >> 6, k = i & 63;
        Wof[((k >> 4) * 64 + n) * 16 + (k & 15)] = f2b(Wo[i]);
      }
    }
  } else {
    // ---- attention block
    unsigned short* Vs = (unsigned short*)smem;
    const int bx = b - 900;
    const int th = bx >> 2;
    {
      const unsigned short* vb = vt + th * 8192;
#pragma unroll
      for (int it = 0; it < 4; ++it) {
        const int flat = (it * 256 + tid) * 8;
        const int d = flat >> 9, k = flat & 511;
        *(int4*)&Vs[d * VPAD + k] = *(const int4*)&vb[flat];
      }
    }
    __syncthreads();

    const int lane = tid & 15;
    const int quad = (tid >> 4) & 3;
    const int w = tid >> 6;
    const int q0 = (bx & 3) * 128 + w * 32;

    const unsigned short* qbase = qh + th * 8192;
    const unsigned short* kbase = kh + th * 8192;
    short4v qf[2];
#pragma unroll
    for (int ct = 0; ct < 2; ++ct)
      qf[ct] = *(const short4v*)&qbase[(q0 + ct * 16 + lane) * 16 + quad * 4];

    float4v acc[2];
    float l[2];
#pragma unroll
    for (int ct = 0; ct < 2; ++ct) {
      acc[ct].x = 0.f; acc[ct].y = 0.f; acc[ct].z = 0.f; acc[ct].w = 0.f;
      l[ct] = 0.f;
    }
    float4v zero;
    zero.x = 0.f; zero.y = 0.f; zero.z = 0.f; zero.w = 0.f;

    const unsigned short* vrow = &Vs[lane * VPAD];

    for (int kt = 0; kt < 32; ++kt) {
      const short4v kf =
          *(const short4v*)&kbase[(kt * 16 + lane) * 16 + quad * 4];
      const short4v vf = *(const short4v*)&vrow[kt * 16 + quad * 4];
#pragma unroll
      for (int ct = 0; ct < 2; ++ct) {
        float4v s = mfma_16x16x16_bf16(kf, qf[ct], zero);
        float p0 = __expf(s.x);
        float p1 = __expf(s.y);
        float p2 = __expf(s.z);
        float p3 = __expf(s.w);
        l[ct] += (p0 + p1) + (p2 + p3);
        unsigned int u0 = __float_as_uint(p0) + 0x8000u;
        unsigned int u1 = __float_as_uint(p1) + 0x8000u;
        unsigned int u2 = __float_as_uint(p2) + 0x8000u;
        unsigned int u3 = __float_as_uint(p3) + 0x8000u;
        union {
          uint2 u;
          short4v s4;
        } pk;
        pk.u.x = __builtin_amdgcn_perm(u1, u0, 0x07060302u);
        pk.u.y = __builtin_amdgcn_perm(u3, u2, 0x07060302u);
        acc[ct] = mfma_16x16x16_bf16(vf, pk.s4, acc[ct]);
      }
    }

    const int t = th >> 2, h = th & 3;
#pragma unroll
    for (int ct = 0; ct < 2; ++ct) {
      float lt = l[ct];
      lt += __shfl_xor(lt, 16, 64);
      lt += __shfl_xor(lt, 32, 64);
      const float inv = 1.f / lt;
      unsigned short tmp[4];
      tmp[0] = f2b(acc[ct].x * inv);
      tmp[1] = f2b(acc[ct].y * inv);
      tmp[2] = f2b(acc[ct].z * inv);
      tmp[3] = f2b(acc[ct].w * inv);
      const int q = q0 + ct * 16 + lane;
      *(uint2*)&obf[(q * 64 + t) * 64 + h * 16 + quad * 4] = *(uint2*)tmp;
    }
  }
}

// ---------------------------------------------------------------------------
// S3: xffn (blocks 0..511, all-MFMA, 42KB LDS)  U  gcn_gemm1 (blocks
// 512..767, zero-LDS, 64m x 128n block tile — R9-verified partition).
// ---------------------------------------------------------------------------
__global__ __launch_bounds__(256) void s3_kernel(
    const unsigned short* __restrict__ obf, const float* __restrict__ query,
    const unsigned short* __restrict__ Wof, const float* __restrict__ bo,
    const float* __restrict__ g1, const float* __restrict__ b1,
    const unsigned short* __restrict__ Wf1f, const float* __restrict__ bf1,
    const unsigned short* __restrict__ Wf2f, const float* __restrict__ bf2,
    const float* __restrict__ g2, const float* __restrict__ b2,
    float* __restrict__ out1, unsigned short* __restrict__ out1b,
    const unsigned short* __restrict__ Ah, const unsigned short* __restrict__ Al,
    const unsigned short* __restrict__ Bh, const unsigned short* __restrict__ Bl,
    const float* __restrict__ bg1, unsigned short* __restrict__ Hh,
    unsigned short* __restrict__ Hl) {
  __shared__ __align__(16) char smem[41984];
  const int tid = threadIdx.x, b = blockIdx.x;
  const int w = tid >> 6, lane = tid & 63;
  const int ln = lane & 15, quad = lane >> 4;
  if (b < 512) {
    unsigned short* xb = (unsigned short*)smem;            // [64*68]
    unsigned short* hid = (unsigned short*)(smem + 8704);  // [64*260]
    const int n = b;
    float xres[4][4];

    // ---- Phase A: x = LN1(obf @ Wo^T + bo + query), MFMA
    {
      const unsigned short* ap = obf + (n * 64 + w * 16 + ln) * 64 + quad * 4;
      float4v acc[4];
#pragma unroll
      for (int j = 0; j < 4; ++j) {
        acc[j].x = 0.f; acc[j].y = 0.f; acc[j].z = 0.f; acc[j].w = 0.f;
      }
#pragma unroll
      for (int kt = 0; kt < 4; ++kt) {
        const short4v a = *(const short4v*)(ap + kt * 16);
#pragma unroll
        for (int j = 0; j < 4; ++j) {
          const short4v bfr =
              *(const short4v*)&Wof[(kt * 64 + j * 16 + ln) * 16 + quad * 4];
          acc[j] = mfma_16x16x16_bf16(a, bfr, acc[j]);
        }
      }
#pragma unroll
      for (int reg = 0; reg < 4; ++reg) {
        const int row = w * 16 + quad * 4 + reg;
        float v[4];
        float s = 0.f;
#pragma unroll
        for (int j = 0; j < 4; ++j) {
          const int col = j * 16 + ln;
          v[j] = acc[j][reg] + bo[col] + query[(n * 64 + row) * 64 + col];
          s += v[j];
        }
        s += __shfl_xor(s, 1, 64);
        s += __shfl_xor(s, 2, 64);
        s += __shfl_xor(s, 4, 64);
        s += __shfl_xor(s, 8, 64);
        const float mean = s * 0.015625f;
        float vv = 0.f;
#pragma unroll
        for (int j = 0; j < 4; ++j) {
          const float dd = v[j] - mean;
          vv += dd * dd;
        }
        vv += __shfl_xor(vv, 1, 64);
        vv += __shfl_xor(vv, 2, 64);
        vv += __shfl_xor(vv, 4, 64);
        vv += __shfl_xor(vv, 8, 64);
        const float rs = rsqrtf(vv * 0.015625f + LN_EPS);
#pragma unroll
        for (int j = 0; j < 4; ++j) {
          const int col = j * 16 + ln;
          const float xv = (v[j] - mean) * rs * g1[col] + b1[col];
          xres[j][reg] = xv;
          xb[row * 68 + col] = f2b(xv);
        }
      }
    }
    __syncthreads();

    // ---- Phase B: hid = relu(x @ Wf1^T + bf1)
    {
      const int wm = (w & 1) * 32, wn = (w >> 1) * 128;
      float4v acc[2][8];
#pragma unroll
      for (int i = 0; i < 2; ++i)
#pragma unroll
        for (int j = 0; j < 8; ++j) {
          acc[i][j].x = 0.f; acc[i][j].y = 0.f;
          acc[i][j].z = 0.f; acc[i][j].w = 0.f;
        }
#pragma unroll
      for (int kt = 0; kt < 4; ++kt) {
        short4v a0 = *(const short4v*)&xb[(wm + ln) * 68 + kt * 16 + quad * 4];
        short4v a1 =
            *(const short4v*)&xb[(wm + 16 + ln) * 68 + kt * 16 + quad * 4];
#pragma unroll
        for (int j = 0; j < 8; ++j) {
          short4v bfr = *(const short4v*)&Wf1f[(kt * 256 + wn + j * 16 + ln) *
                                                   16 + quad * 4];
          acc[0][j] = mfma_16x16x16_bf16(a0, bfr, acc[0][j]);
          acc[1][j] = mfma_16x16x16_bf16(a1, bfr, acc[1][j]);
        }
      }
#pragma unroll
      for (int mt = 0; mt < 2; ++mt)
#pragma unroll
        for (int j = 0; j < 8; ++j) {
          const int col = wn + j * 16 + ln;
          const float bb = bf1[col];
#pragma unroll
          for (int reg = 0; reg < 4; ++reg) {
            const int row = wm + mt * 16 + quad * 4 + reg;
            hid[row * 260 + col] = f2b(fmaxf(acc[mt][j][reg] + bb, 0.f));
          }
        }
    }
    __syncthreads();

    // ---- Phase C: out1 = LN2(hid @ Wf2^T + bf2 + x)
    {
      float4v acc[4];
#pragma unroll
      for (int j = 0; j < 4; ++j) {
        acc[j].x = 0.f; acc[j].y = 0.f; acc[j].z = 0.f; acc[j].w = 0.f;
      }
#pragma unroll 4
      for (int kt = 0; kt < 16; ++kt) {
        short4v a =
            *(const short4v*)&hid[(w * 16 + ln) * 260 + kt * 16 + quad * 4];
#pragma unroll
        for (int j = 0; j < 4; ++j) {
          short4v bfr =
              *(const short4v*)&Wf2f[(kt * 64 + j * 16 + ln) * 16 + quad * 4];
          acc[j] = mfma_16x16x16_bf16(a, bfr, acc[j]);
        }
      }
#pragma unroll
      for (int reg = 0; reg < 4; ++reg) {
        const int row = w * 16 + quad * 4 + reg;
        float v[4];
        float s = 0.f;
#pragma unroll
        for (int j = 0; j < 4; ++j) {
          v[j] = acc[j][reg] + bf2[j * 16 + ln] + xres[j][reg];
          s += v[j];
        }
        s += __shfl_xor(s, 1, 64);
        s += __shfl_xor(s, 2, 64);
        s += __shfl_xor(s, 4, 64);
        s += __shfl_xor(s, 8, 64);
        const float mean = s * 0.015625f;
        float vv = 0.f;
#pragma unroll
        for (int j = 0; j < 4; ++j) {
          const float dd = v[j] - mean;
          vv += dd * dd;
        }
        vv += __shfl_xor(vv, 1, 64);
        vv += __shfl_xor(vv, 2, 64);
        vv += __shfl_xor(vv, 4, 64);
        vv += __shfl_xor(vv, 8, 64);
        const float rs = rsqrtf(vv * 0.015625f + LN_EPS);
#pragma unroll
        for (int j = 0; j < 4; ++j) {
          const float ov =
              (v[j] - mean) * rs * g2[j * 16 + ln] + b2[j * 16 + ln];
          const int idx = (n * 64 + row) * 64 + j * 16 + ln;
          out1[idx] = ov;
          out1b[idx] = f2b(ov);
        }
      }
    }
  } else {
    // ---- gcn_gemm1 block (zero LDS, R9 partition: 64m x 128n)
    const int pb = b - 512;
    const int wave = w;
    const int wm = (wave & 1) * 32, wn = (wave >> 1) * 64;
    const int m0 = (pb >> 5) * 64 + wm;
    const int n0 = (pb & 31) * 128 + wn;

    const unsigned short* ah0 = Ah + (m0 + ln) * 512 + quad * 4;
    const unsigned short* al0 = Al + (m0 + ln) * 512 + quad * 4;
    const unsigned short* bh0 = Bh + (n0 + ln) * 16 + quad * 4;
    const unsigned short* bl0 = Bl + (n0 + ln) * 16 + quad * 4;

    float4v acc[2][4];
#pragma unroll
    for (int i = 0; i < 2; ++i)
#pragma unroll
      for (int j = 0; j < 4; ++j) {
        acc[i][j].x = 0.f; acc[i][j].y = 0.f;
        acc[i][j].z = 0.f; acc[i][j].w = 0.f;
      }

#pragma unroll 2
    for (int kt = 0; kt < 32; ++kt) {
      short4v a0h = *(const short4v*)(ah0 + kt * 16);
      short4v a1h = *(const short4v*)(ah0 + 16 * 512 + kt * 16);
      short4v a0l = *(const short4v*)(al0 + kt * 16);
      short4v a1l = *(const short4v*)(al0 + 16 * 512 + kt * 16);
#pragma unroll
      for (int j = 0; j < 4; ++j) {
        const int boff = (kt * 4096 + j * 16) * 16;
        short4v bh = *(const short4v*)(bh0 + boff);
        short4v bl = *(const short4v*)(bl0 + boff);
        acc[0][j] = mfma_16x16x16_bf16(a0l, bh, acc[0][j]);
        acc[0][j] = mfma_16x16x16_bf16(a0h, bl, acc[0][j]);
        acc[0][j] = mfma_16x16x16_bf16(a0h, bh, acc[0][j]);
        acc[1][j] = mfma_16x16x16_bf16(a1l, bh, acc[1][j]);
        acc[1][j] = mfma_16x16x16_bf16(a1h, bl, acc[1][j]);
        acc[1][j] = mfma_16x16x16_bf16(a1h, bh, acc[1][j]);
      }
    }

#pragma unroll
    for (int mt = 0; mt < 2; ++mt) {
      const int mtile = (m0 + mt * 16) >> 4;
#pragma unroll
      for (int j = 0; j < 4; ++j) {
        const int col = n0 + j * 16 + ln;
        const float bb = bg1[col & 63];
        unsigned short hh[4], hl[4];
#pragma unroll
        for (int reg = 0; reg < 4; ++reg) {
          float v = fmaxf(acc[mt][j][reg] + bb, 0.f);
          hh[reg] = f2b(v);
          hl[reg] = f2b(v - b2f(hh[reg]));
        }
        const int off = (mtile * 4096 + col) * 16 + quad * 4;
        *(uint2*)&Hh[off] = *(uint2*)hh;
        *(uint2*)&Hl[off] = *(uint2*)hl;
      }
    }
  }
}

// ---------------------------------------------------------------------------
// S45: fused GEMM2 + gate. 512 blocks: block = 64 n-rows x 64 cols (one t).
// Phase 1: G2 tile = adj_n @ Hr (split MFMA, 3 independent acc sets) -> LDS
// f32. Phase 2: per-wave gate (R7-verified numerics): split G2 from LDS,
// out2 = G2@Wg2^T + bg2; a = out1@Wo1^T + G2@W32^T + c2;
// dst = o2 + sigmoid(a)*(o1-o2).
// ---------------------------------------------------------------------------
__global__ __launch_bounds__(256) void s45_kernel(
    const unsigned short* __restrict__ Ah, const unsigned short* __restrict__ Al,
    const unsigned short* __restrict__ Bh, const unsigned short* __restrict__ Bl,
    const unsigned short* __restrict__ out1b, const float* __restrict__ out1,
    const unsigned short* __restrict__ Wo1f, const unsigned short* __restrict__ Wg2hf,
    const unsigned short* __restrict__ Wg2lf, const unsigned short* __restrict__ W32hf,
    const unsigned short* __restrict__ W32lf, const float* __restrict__ bg2,
    const float* __restrict__ c2, float* __restrict__ dst) {
  __shared__ __align__(16) float Ls[64 * 68];
  const int tid = threadIdx.x;
  const int wave = tid >> 6, lane = tid & 63;
  const int ln = lane & 15, quad = lane >> 4;
  const int N0 = (blockIdx.x >> 6) * 64;
  const int t = blockIdx.x & 63;

  // ---- Phase 1: split GEMM, wave tile 32m x 32n, 3 independent acc sets
  {
    const int wm = (wave & 1) * 32, wn = (wave >> 1) * 32;
    const int m0 = N0 + wm;
    const int n0 = t * 64 + wn;
    const unsigned short* ah0 = Ah + (m0 + ln) * 512 + quad * 4;
    const unsigned short* al0 = Al + (m0 + ln) * 512 + quad * 4;
    const unsigned short* bh0 = Bh + (n0 + ln) * 16 + quad * 4;
    const unsigned short* bl0 = Bl + (n0 + ln) * 16 + quad * 4;

    float4v ahh[2][2], ahl[2][2], alh[2][2];
#pragma unroll
    for (int i = 0; i < 2; ++i)
#pragma unroll
      for (int j = 0; j < 2; ++j) {
        ahh[i][j].x = 0.f; ahh[i][j].y = 0.f;
        ahh[i][j].z = 0.f; ahh[i][j].w = 0.f;
        ahl[i][j] = ahh[i][j];
        alh[i][j] = ahh[i][j];
      }

#pragma unroll 4
    for (int kt = 0; kt < 32; ++kt) {
      short4v a0h = *(const short4v*)(ah0 + kt * 16);
      short4v a1h = *(const short4v*)(ah0 + 16 * 512 + kt * 16);
      short4v a0l = *(const short4v*)(al0 + kt * 16);
      short4v a1l = *(const short4v*)(al0 + 16 * 512 + kt * 16);
#pragma unroll
      for (int j = 0; j < 2; ++j) {
        const int boff = (kt * 4096 + j * 16) * 16;
        short4v bh = *(const short4v*)(bh0 + boff);
        short4v bl = *(const short4v*)(bl0 + boff);
        ahh[0][j] = mfma_16x16x16_bf16(a0h, bh, ahh[0][j]);
        ahl[0][j] = mfma_16x16x16_bf16(a0h, bl, ahl[0][j]);
        alh[0][j] = mfma_16x16x16_bf16(a0l, bh, alh[0][j]);
        ahh[1][j] = mfma_16x16x16_bf16(a1h, bh, ahh[1][j]);
        ahl[1][j] = mfma_16x16x16_bf16(a1h, bl, ahl[1][j]);
        alh[1][j] = mfma_16x16x16_bf16(a1l, bh, alh[1][j]);
      }
    }

#pragma unroll
    for (int mt = 0; mt < 2; ++mt)
#pragma unroll
      for (int j = 0; j < 2; ++j) {
        const int c = wn + j * 16 + ln;
#pragma unroll
        for (int reg = 0; reg < 4; ++reg) {
          const int r = wm + mt * 16 + quad * 4 + reg;
          Ls[r * 68 + c] =
              ahh[mt][j][reg] + ahl[mt][j][reg] + alh[mt][j][reg];
        }
      }
  }
  __syncthreads();

  // ---- Phase 2: gate for rows wave*16 .. wave*16+15 (node-local)
  {
    const int rloc = wave * 16;
    float4v aco[4], aca[4];
#pragma unroll
    for (int j = 0; j < 4; ++j) {
      aco[j].x = 0.f; aco[j].y = 0.f; aco[j].z = 0.f; aco[j].w = 0.f;
      aca[j].x = 0.f; aca[j].y = 0.f; aca[j].z = 0.f; aca[j].w = 0.f;
    }
    const unsigned short* o1p =
        out1b + ((N0 + rloc + ln) * 64 + t) * 64 + quad * 4;

#pragma unroll
    for (int kt = 0; kt < 4; ++kt) {
      // split G2 fragment from LDS f32 (same values as stored G2h/G2l)
      float4 gv = *(const float4*)&Ls[(rloc + ln) * 68 + kt * 16 + quad * 4];
      unsigned short ghv[4], glv[4];
      {
        const float g4[4] = {gv.x, gv.y, gv.z, gv.w};
#pragma unroll
        for (int e = 0; e < 4; ++e) {
          ghv[e] = f2b(g4[e]);
          glv[e] = f2b(g4[e] - b2f(ghv[e]));
        }
      }
      const short4v gh = *(short4v*)ghv;
      const short4v gl = *(short4v*)glv;
      const short4v ao = *(const short4v*)(o1p + kt * 16);
#pragma unroll
      for (int j = 0; j < 4; ++j) {
        const int boff = (kt * 64 + j * 16 + ln) * 16 + quad * 4;
        const short4v wgh = *(const short4v*)(Wg2hf + boff);
        const short4v wgl = *(const short4v*)(Wg2lf + boff);
        const short4v wo1 = *(const short4v*)(Wo1f + boff);
        const short4v w3h = *(const short4v*)(W32hf + boff);
        const short4v w3l = *(const short4v*)(W32lf + boff);
        aco[j] = mfma_16x16x16_bf16(gl, wgh, aco[j]);
        aco[j] = mfma_16x16x16_bf16(gh, wgl, aco[j]);
        aco[j] = mfma_16x16x16_bf16(gh, wgh, aco[j]);
        aca[j] = mfma_16x16x16_bf16(ao, wo1, aca[j]);
        aca[j] = mfma_16x16x16_bf16(gl, w3h, aca[j]);
        aca[j] = mfma_16x16x16_bf16(gh, w3l, aca[j]);
        aca[j] = mfma_16x16x16_bf16(gh, w3h, aca[j]);
      }
    }

#pragma unroll
    for (int j = 0; j < 4; ++j) {
      const int col = j * 16 + ln;
      const float bg2v = bg2[col];
      const float c2v = c2[col];
#pragma unroll
      for (int reg = 0; reg < 4; ++reg) {
        const int rowg = (N0 + rloc + quad * 4 + reg) * 64 + t;
        const float o2 = aco[j][reg] + bg2v;
        const float a = aca[j][reg] + c2v;
        const float o1v = out1[rowg * 64 + col];
        const float g = 1.f / (1.f + __expf(-a));
        dst[rowg * 64 + col] = o2 + g * (o1v - o2);
      }
    }
  }
}

// ---------------------------------------------------------------------------
extern "C" void kernel_launch(void* const* d_in, const int* in_sizes, int n_in,
                              void* d_out, int out_size, void* d_ws,
                              size_t ws_size, hipStream_t stream) {
  const float* value = (const float*)d_in[0];
  const float* key_t = (const float*)d_in[1];
  const float* query = (const float*)d_in[2];
  const float* adj = (const float*)d_in[3];
  const float* Wv = (const float*)d_in[4];
  const float* Wk = (const float*)d_in[5];
  const float* Wq = (const float*)d_in[6];
  const float* Wo = (const float*)d_in[7];
  const float* bo = (const float*)d_in[8];
  const float* g1 = (const float*)d_in[9];
  const float* b1 = (const float*)d_in[10];
  const float* g2 = (const float*)d_in[11];
  const float* b2 = (const float*)d_in[12];
  const float* Wf1 = (const float*)d_in[13];
  const float* bf1 = (const float*)d_in[14];
  const float* Wf2 = (const float*)d_in[15];
  const float* bf2 = (const float*)d_in[16];
  const float* Wg1 = (const float*)d_in[17];
  const float* bg1 = (const float*)d_in[18];
  const float* Wg2 = (const float*)d_in[19];
  const float* bg2 = (const float*)d_in[20];
  const float* Wo1 = (const float*)d_in[21];
  const float* bo1 = (const float*)d_in[22];
  const float* Wo2 = (const float*)d_in[23];
  const float* bo2 = (const float*)d_in[24];

  float* ws = (float*)d_ws;
  const size_t M1 = 1048576;
  unsigned short* obf = (unsigned short*)(ws + 0);          // [0,1M) bf16
  float* out1 = ws + 2 * M1;                                // [2M,4M)
  unsigned short* out1b = (unsigned short*)(ws + 4 * M1);   // [4M,5M)
  unsigned short* qh = (unsigned short*)(ws + 5 * M1);
  unsigned short* kh = (unsigned short*)(ws + 6 * M1);
  unsigned short* vt = (unsigned short*)(ws + 7 * M1);
  unsigned short* Yfh = (unsigned short*)(ws + 8 * M1);
  unsigned short* Yfl = (unsigned short*)(ws + 9 * M1);
  unsigned short* Hrfh = (unsigned short*)(ws + 10 * M1);
  unsigned short* Hrfl = (unsigned short*)(ws + 11 * M1);
  unsigned short* anh = (unsigned short*)(ws + 14 * M1);
  unsigned short* anl = (unsigned short*)(ws + 14 * M1 + 131072);
  float* wbase = ws + 14 * M1 + 262144;
  unsigned short* Wf1f = (unsigned short*)(wbase);
  unsigned short* Wf2f = (unsigned short*)(wbase + 8192);
  unsigned short* Wo1f = (unsigned short*)(wbase + 16384);
  unsigned short* Wg2hf = (unsigned short*)(wbase + 18432);
  unsigned short* Wg2lf = (unsigned short*)(wbase + 20480);
  unsigned short* W32hf = (unsigned short*)(wbase + 22528);
  unsigned short* W32lf = (unsigned short*)(wbase + 24576);
  unsigned short* Wof = (unsigned short*)(wbase + 26624);
  float* c2 = wbase + 28672;
  float* ps = wbase + 28736;
  float* pss = ps + 512;
  float* dst = (float*)d_out;

  s1_kernel<<<768, 256, 0, stream>>>(adj, ps, pss, value, key_t, query, Wv,
                                     Wk, Wq, vt, kh, qh);
  s2_kernel<<<1924, 256, 0, stream>>>(adj, ps, pss, query, Wg1, Wf1, Wf2, Wo1,
                                      Wo2, Wg2, Wo, bg2, bo1, bo2, anh, anl,
                                      Yfh, Yfl, Wf1f, Wf2f, Wo1f, Wg2hf,
                                      Wg2lf, W32hf, W32lf, Wof, c2, qh, kh,
                                      vt, obf);
  s3_kernel<<<768, 256, 0, stream>>>(obf, query, Wof, bo, g1, b1, Wf1f, bf1,
                                     Wf2f, bf2, g2, b2, out1, out1b, anh, anl,
                                     Yfh, Yfl, bg1, Hrfh, Hrfl);
  s45_kernel<<<512, 256, 0, stream>>>(anh, anl, Hrfh, Hrfl, out1b, out1,
                                      Wo1f, Wg2hf, Wg2lf, W32hf, W32lf, bg2,
                                      c2, dst);
}